// Round 1
// baseline (447.227 us; speedup 1.0000x reference)
//
#include <hip/hip_runtime.h>

typedef unsigned short u16;
typedef __attribute__((ext_vector_type(8))) short short8;
typedef __attribute__((ext_vector_type(8))) unsigned short ushort8v;
typedef __attribute__((ext_vector_type(4))) float f32x4;

#define B_ 8
#define T_ 256
#define U_ 64
#define E_ 512
#define J_ 640
#define V_ 1024

__device__ __forceinline__ u16 f2bf(float f) {
  unsigned int u = __float_as_uint(f);
  u += 0x7fffu + ((u >> 16) & 1u);   // round-to-nearest-even
  return (u16)(u >> 16);
}

__device__ __forceinline__ void gload16(const void* g, void* l) {
  __builtin_amdgcn_global_load_lds((const __attribute__((address_space(1))) void*)g,
                                   (__attribute__((address_space(3))) void*)l,
                                   16, 0, 0);
}

// ---------------- cast fp32 -> bf16 ----------------
__global__ __launch_bounds__(256) void cast_k(const float4* __restrict__ src,
                                              ushort4* __restrict__ dst, int n4) {
  int i = blockIdx.x * 256 + threadIdx.x;
  int st = gridDim.x * 256;
  for (; i < n4; i += st) {
    float4 v = src[i];
    ushort4 o;
    o.x = f2bf(v.x); o.y = f2bf(v.y); o.z = f2bf(v.z); o.w = f2bf(v.w);
    dst[i] = o;
  }
}

// ---------------- projection GEMM: C[M][640] = X[M][512](bf16) @ W[640][512](bf16)^T, fp32 out
// 128x128 tile, BK=32, 4 waves. Both tiles via global_load_lds (linear [128][32]).
__global__ __launch_bounds__(256) void proj_k(const u16* __restrict__ X,
                                              const u16* __restrict__ W,
                                              float* __restrict__ C) {
  __shared__ __align__(16) u16 As[128 * 32];
  __shared__ __align__(16) u16 Bs[128 * 32];
  const int tid = threadIdx.x;
  const int w = tid >> 6, lane = tid & 63;
  const int wr = w >> 1, wc = w & 1;
  const int m0 = blockIdx.x * 128, n0 = blockIdx.y * 128;
  const int lr = lane & 15, lk = lane >> 4;
  const int r4 = tid >> 2, kq = tid & 3;

  f32x4 acc[4][4] = {};

  for (int ks = 0; ks < E_ / 32; ++ks) {
    const int k0 = ks * 32;
    gload16(X + (size_t)(m0 + r4) * E_ + k0 + kq * 8, (char*)As + w * 1024);
    gload16(X + (size_t)(m0 + 64 + r4) * E_ + k0 + kq * 8, (char*)As + 4096 + w * 1024);
    gload16(W + (size_t)(n0 + r4) * E_ + k0 + kq * 8, (char*)Bs + w * 1024);
    gload16(W + (size_t)(n0 + 64 + r4) * E_ + k0 + kq * 8, (char*)Bs + 4096 + w * 1024);
    __syncthreads();
    short8 a[4], bb[4];
#pragma unroll
    for (int m = 0; m < 4; ++m)
      a[m] = *(const short8*)&As[(wr * 64 + m * 16 + lr) * 32 + lk * 8];
#pragma unroll
    for (int n = 0; n < 4; ++n)
      bb[n] = *(const short8*)&Bs[(wc * 64 + n * 16 + lr) * 32 + lk * 8];
#pragma unroll
    for (int m = 0; m < 4; ++m)
#pragma unroll
      for (int n = 0; n < 4; ++n)
        acc[m][n] = __builtin_amdgcn_mfma_f32_16x16x32_bf16(a[m], bb[n], acc[m][n], 0, 0, 0);
    __syncthreads();
  }

#pragma unroll
  for (int m = 0; m < 4; ++m) {
    const int row = m0 + wr * 64 + m * 16 + lk * 4;
#pragma unroll
    for (int n = 0; n < 4; ++n) {
      const int col = n0 + wc * 64 + n * 16 + lr;
#pragma unroll
      for (int i = 0; i < 4; ++i)
        C[(size_t)(row + i) * J_ + col] = acc[m][n][i];
    }
  }
}

// ---------------- fused joint GEMM ----------------
// out[m][v] = sum_k silu(ep[bt][k] + pp[bu][k]) * Wo[v][k]
// M = 131072 (b,t,u), tile 128x128, BK=32, 4 waves.
// A-tile computed in-kernel (silu) -> LDS stride 40 (bank-spread); B via global_load_lds.
__global__ __launch_bounds__(256) void joint_k(const float* __restrict__ ep,
                                               const float* __restrict__ pp,
                                               const u16* __restrict__ Wo,
                                               float* __restrict__ out) {
  __shared__ __align__(16) u16 As[128 * 40];
  __shared__ __align__(16) u16 Bs[128 * 32];
  const int tid = threadIdx.x;
  const int w = tid >> 6, lane = tid & 63;
  const int wr = w >> 1, wc = w & 1;
  const int bid = blockIdx.x;
  const int nb = bid & 7;        // 8 N-blocks of 128
  const int mb = bid >> 3;       // 1024 M-blocks of 128 rows
  const int b = mb >> 7;         // 128 M-blocks per batch
  const int t0 = (mb & 127) * 2; // each block: 2 t values x 64 u values
  const int n0 = nb * 128;
  const int lr = lane & 15, lk = lane >> 4;

  // A staging: thread -> (row r, k-half h), 16 elements each
  const int r = tid >> 1, h = tid & 1;
  const float* eprow = ep + (size_t)((b * T_ + t0 + (r >> 6)) * J_ + h * 16);
  const float* pprow = pp + (size_t)((b * U_ + (r & 63)) * J_ + h * 16);
  u16* awp = &As[r * 40 + h * 16];
  // B staging via gload_lds
  const int r4 = tid >> 2, kq = tid & 3;

  f32x4 acc[4][4] = {};

  for (int ks = 0; ks < J_ / 32; ++ks) {
    const int k0 = ks * 32;
    // B tile (issue first: latency overlaps with silu compute below)
    gload16(Wo + (size_t)(n0 + r4) * J_ + k0 + kq * 8, (char*)Bs + w * 1024);
    gload16(Wo + (size_t)(n0 + 64 + r4) * J_ + k0 + kq * 8, (char*)Bs + 4096 + w * 1024);
    // A tile: silu(ep+pp) -> bf16 -> LDS
    union { float4 v[4]; float f[16]; } Ee, Pp;
#pragma unroll
    for (int j = 0; j < 4; ++j) {
      Ee.v[j] = *(const float4*)(eprow + k0 + j * 4);
      Pp.v[j] = *(const float4*)(pprow + k0 + j * 4);
    }
    union { ushort8v v[2]; u16 s[16]; } R;
#pragma unroll
    for (int j = 0; j < 16; ++j) {
      float x = Ee.f[j] + Pp.f[j];
      float s = x * __builtin_amdgcn_rcpf(1.0f + __expf(-x));
      R.s[j] = f2bf(s);
    }
    *(ushort8v*)awp = R.v[0];
    *(ushort8v*)(awp + 8) = R.v[1];
    __syncthreads();

    short8 a[4], bb[4];
#pragma unroll
    for (int m = 0; m < 4; ++m)
      a[m] = *(const short8*)&As[(wr * 64 + m * 16 + lr) * 40 + lk * 8];
#pragma unroll
    for (int n = 0; n < 4; ++n)
      bb[n] = *(const short8*)&Bs[(wc * 64 + n * 16 + lr) * 32 + lk * 8];
#pragma unroll
    for (int m = 0; m < 4; ++m)
#pragma unroll
      for (int n = 0; n < 4; ++n)
        acc[m][n] = __builtin_amdgcn_mfma_f32_16x16x32_bf16(a[m], bb[n], acc[m][n], 0, 0, 0);
    __syncthreads();
  }

  const size_t mbase = (size_t)mb * 128;
#pragma unroll
  for (int m = 0; m < 4; ++m) {
    const size_t row = mbase + wr * 64 + m * 16 + lk * 4;
#pragma unroll
    for (int n = 0; n < 4; ++n) {
      const int col = n0 + wc * 64 + n * 16 + lr;
#pragma unroll
      for (int i = 0; i < 4; ++i)
        out[(row + i) * V_ + col] = acc[m][n][i];
    }
  }
}

extern "C" void kernel_launch(void* const* d_in, const int* in_sizes, int n_in,
                              void* d_out, int out_size, void* d_ws, size_t ws_size,
                              hipStream_t stream) {
  const float* enc = (const float*)d_in[0];   // [8,256,512]
  const float* pred = (const float*)d_in[1];  // [8,64,512]
  const float* We = (const float*)d_in[2];    // [640,512]
  const float* Wp = (const float*)d_in[3];    // [640,512]
  const float* Wo = (const float*)d_in[4];    // [1024,640]
  float* out = (float*)d_out;                 // [8,256,64,1024]

  char* ws = (char*)d_ws;
  u16* enc_bf = (u16*)ws;                     // 2,097,152 B
  u16* pred_bf = (u16*)(ws + 2097152);        //   524,288 B
  u16* We_bf = (u16*)(ws + 2621440);          //   655,360 B
  u16* Wp_bf = (u16*)(ws + 3276800);          //   655,360 B
  u16* Wo_bf = (u16*)(ws + 3932160);          // 1,310,720 B
  float* ep = (float*)(ws + 5242880);         // 5,242,880 B  [2048][640]
  float* pp = (float*)(ws + 10485760);        // 1,310,720 B  [512][640]
  // total ws use: 11,796,480 B

  cast_k<<<1024, 256, 0, stream>>>((const float4*)enc, (ushort4*)enc_bf, 262144);
  cast_k<<<256, 256, 0, stream>>>((const float4*)pred, (ushort4*)pred_bf, 65536);
  cast_k<<<320, 256, 0, stream>>>((const float4*)We, (ushort4*)We_bf, 81920);
  cast_k<<<320, 256, 0, stream>>>((const float4*)Wp, (ushort4*)Wp_bf, 81920);
  cast_k<<<640, 256, 0, stream>>>((const float4*)Wo, (ushort4*)Wo_bf, 163840);

  proj_k<<<dim3(16, 5), 256, 0, stream>>>(enc_bf, We_bf, ep);  // [2048][640]
  proj_k<<<dim3(4, 5), 256, 0, stream>>>(pred_bf, Wp_bf, pp);  // [512][640]

  joint_k<<<8192, 256, 0, stream>>>(ep, pp, Wo_bf, out);
}

// Round 2
// 446.844 us; speedup vs baseline: 1.0009x; 1.0009x over previous
//
#include <hip/hip_runtime.h>

typedef unsigned short u16;
typedef __attribute__((ext_vector_type(8))) short short8;
typedef __attribute__((ext_vector_type(8))) unsigned short ushort8v;
typedef __attribute__((ext_vector_type(4))) float f32x4;

#define B_ 8
#define T_ 256
#define U_ 64
#define E_ 512
#define J_ 640
#define V_ 1024

__device__ __forceinline__ u16 f2bf(float f) {
  unsigned int u = __float_as_uint(f);
  u += 0x7fffu + ((u >> 16) & 1u);   // round-to-nearest-even
  return (u16)(u >> 16);
}

__device__ __forceinline__ void gload16(const void* g, void* l) {
  __builtin_amdgcn_global_load_lds((const __attribute__((address_space(1))) void*)g,
                                   (__attribute__((address_space(3))) void*)l,
                                   16, 0, 0);
}

// ---------------- cast fp32 -> bf16 ----------------
__global__ __launch_bounds__(256) void cast_k(const float4* __restrict__ src,
                                              ushort4* __restrict__ dst, int n4) {
  int i = blockIdx.x * 256 + threadIdx.x;
  int st = gridDim.x * 256;
  for (; i < n4; i += st) {
    float4 v = src[i];
    ushort4 o;
    o.x = f2bf(v.x); o.y = f2bf(v.y); o.z = f2bf(v.z); o.w = f2bf(v.w);
    dst[i] = o;
  }
}

// ---------------- projection GEMM: C[M][640] = X[M][512](bf16) @ W[640][512](bf16)^T, fp32 out
__global__ __launch_bounds__(256) void proj_k(const u16* __restrict__ X,
                                              const u16* __restrict__ W,
                                              float* __restrict__ C) {
  __shared__ __align__(16) u16 As[128 * 32];
  __shared__ __align__(16) u16 Bs[128 * 32];
  const int tid = threadIdx.x;
  const int w = tid >> 6, lane = tid & 63;
  const int wr = w >> 1, wc = w & 1;
  const int m0 = blockIdx.x * 128, n0 = blockIdx.y * 128;
  const int lr = lane & 15, lk = lane >> 4;
  const int r4 = tid >> 2, kq = tid & 3;

  f32x4 acc[4][4] = {};

  for (int ks = 0; ks < E_ / 32; ++ks) {
    const int k0 = ks * 32;
    gload16(X + (size_t)(m0 + r4) * E_ + k0 + kq * 8, (char*)As + w * 1024);
    gload16(X + (size_t)(m0 + 64 + r4) * E_ + k0 + kq * 8, (char*)As + 4096 + w * 1024);
    gload16(W + (size_t)(n0 + r4) * E_ + k0 + kq * 8, (char*)Bs + w * 1024);
    gload16(W + (size_t)(n0 + 64 + r4) * E_ + k0 + kq * 8, (char*)Bs + 4096 + w * 1024);
    __syncthreads();
    short8 a[4], bb[4];
#pragma unroll
    for (int m = 0; m < 4; ++m)
      a[m] = *(const short8*)&As[(wr * 64 + m * 16 + lr) * 32 + lk * 8];
#pragma unroll
    for (int n = 0; n < 4; ++n)
      bb[n] = *(const short8*)&Bs[(wc * 64 + n * 16 + lr) * 32 + lk * 8];
#pragma unroll
    for (int m = 0; m < 4; ++m)
#pragma unroll
      for (int n = 0; n < 4; ++n)
        acc[m][n] = __builtin_amdgcn_mfma_f32_16x16x32_bf16(a[m], bb[n], acc[m][n], 0, 0, 0);
    __syncthreads();
  }

#pragma unroll
  for (int m = 0; m < 4; ++m) {
    const int row = m0 + wr * 64 + m * 16 + lk * 4;
#pragma unroll
    for (int n = 0; n < 4; ++n) {
      const int col = n0 + wc * 64 + n * 16 + lr;
#pragma unroll
      for (int i = 0; i < 4; ++i)
        C[(size_t)(row + i) * J_ + col] = acc[m][n][i];
    }
  }
}

// ---------------- A materializer: A[m][k] = bf16(silu(ep[bt][k] + pp[bu][k])) ----------------
// m = b*16384 + t*64 + u ; 8 k-elements per unit, 10,485,760 units total.
__global__ __launch_bounds__(256) void silu_k(const float* __restrict__ ep,
                                              const float* __restrict__ pp,
                                              u16* __restrict__ A, int nUnits) {
  int i = blockIdx.x * 256 + threadIdx.x;
  const int st = gridDim.x * 256;
  for (; i < nUnits; i += st) {
    const int m = i / 80;            // magic-mul
    const int k0 = (i - m * 80) * 8;
    const int b = m >> 14;
    const int t = (m >> 6) & 255;
    const int uu = m & 63;
    const float* e = ep + (size_t)(b * T_ + t) * J_ + k0;
    const float* p = pp + (size_t)(b * U_ + uu) * J_ + k0;
    union { float4 v[2]; float f[8]; } Ee, Pp;
    Ee.v[0] = *(const float4*)e;      Ee.v[1] = *(const float4*)(e + 4);
    Pp.v[0] = *(const float4*)p;      Pp.v[1] = *(const float4*)(p + 4);
    union { ushort8v v; u16 s[8]; } R;
#pragma unroll
    for (int j = 0; j < 8; ++j) {
      float x = Ee.f[j] + Pp.f[j];
      float s = x * __builtin_amdgcn_rcpf(1.0f + __expf(-x));
      R.s[j] = f2bf(s);
    }
    *(ushort8v*)(A + (size_t)m * J_ + k0) = R.v;
  }
}

// ---------------- main GEMM: out[M=131072][1024] = A[M][640] @ Wo[1024][640]^T ----------------
// 128x128 tile, BK=32, 4 waves, both operands via global_load_lds(16B). XCD-swizzled grid.
__global__ __launch_bounds__(256) void gemm_k(const u16* __restrict__ A,
                                              const u16* __restrict__ Bw,
                                              float* __restrict__ out) {
  __shared__ __align__(16) u16 As[128 * 32];
  __shared__ __align__(16) u16 Bs[128 * 32];
  const int tid = threadIdx.x;
  const int w = tid >> 6, lane = tid & 63;
  const int wr = w >> 1, wc = w & 1;
  // XCD-aware swizzle: nwg=8192, 8 XCDs, contiguous 1024-wid chunk per XCD
  const int bid = blockIdx.x;
  const int wid = (bid & 7) * 1024 + (bid >> 3);
  const int mb = wid >> 3, nb = wid & 7;
  const size_t m0 = (size_t)mb * 128;
  const int n0 = nb * 128;
  const int lr = lane & 15, lk = lane >> 4;
  const int r4 = tid >> 2, kq = tid & 3;

  f32x4 acc[4][4] = {};

  for (int ks = 0; ks < J_ / 32; ++ks) {
    const int k0 = ks * 32;
    gload16(A + (m0 + r4) * J_ + k0 + kq * 8, (char*)As + w * 1024);
    gload16(A + (m0 + 64 + r4) * J_ + k0 + kq * 8, (char*)As + 4096 + w * 1024);
    gload16(Bw + (size_t)(n0 + r4) * J_ + k0 + kq * 8, (char*)Bs + w * 1024);
    gload16(Bw + (size_t)(n0 + 64 + r4) * J_ + k0 + kq * 8, (char*)Bs + 4096 + w * 1024);
    __syncthreads();
    short8 a[4], bb[4];
#pragma unroll
    for (int m = 0; m < 4; ++m)
      a[m] = *(const short8*)&As[(wr * 64 + m * 16 + lr) * 32 + lk * 8];
#pragma unroll
    for (int n = 0; n < 4; ++n)
      bb[n] = *(const short8*)&Bs[(wc * 64 + n * 16 + lr) * 32 + lk * 8];
#pragma unroll
    for (int m = 0; m < 4; ++m)
#pragma unroll
      for (int n = 0; n < 4; ++n)
        acc[m][n] = __builtin_amdgcn_mfma_f32_16x16x32_bf16(a[m], bb[n], acc[m][n], 0, 0, 0);
    __syncthreads();
  }

#pragma unroll
  for (int m = 0; m < 4; ++m) {
    const size_t row = m0 + wr * 64 + m * 16 + lk * 4;
#pragma unroll
    for (int n = 0; n < 4; ++n) {
      const int col = n0 + wc * 64 + n * 16 + lr;
#pragma unroll
      for (int i = 0; i < 4; ++i)
        out[(row + i) * V_ + col] = acc[m][n][i];
    }
  }
}

// ---------------- fallback fused kernel (round-1) if ws too small ----------------
__global__ __launch_bounds__(256) void joint_k(const float* __restrict__ ep,
                                               const float* __restrict__ pp,
                                               const u16* __restrict__ Wo,
                                               float* __restrict__ out) {
  __shared__ __align__(16) u16 As[128 * 40];
  __shared__ __align__(16) u16 Bs[128 * 32];
  const int tid = threadIdx.x;
  const int w = tid >> 6, lane = tid & 63;
  const int wr = w >> 1, wc = w & 1;
  const int bid = blockIdx.x;
  const int nb = bid & 7;
  const int mb = bid >> 3;
  const int b = mb >> 7;
  const int t0 = (mb & 127) * 2;
  const int n0 = nb * 128;
  const int lr = lane & 15, lk = lane >> 4;
  const int r = tid >> 1, h = tid & 1;
  const float* eprow = ep + (size_t)((b * T_ + t0 + (r >> 6)) * J_ + h * 16);
  const float* pprow = pp + (size_t)((b * U_ + (r & 63)) * J_ + h * 16);
  u16* awp = &As[r * 40 + h * 16];
  const int r4 = tid >> 2, kq = tid & 3;

  f32x4 acc[4][4] = {};

  for (int ks = 0; ks < J_ / 32; ++ks) {
    const int k0 = ks * 32;
    gload16(Wo + (size_t)(n0 + r4) * J_ + k0 + kq * 8, (char*)Bs + w * 1024);
    gload16(Wo + (size_t)(n0 + 64 + r4) * J_ + k0 + kq * 8, (char*)Bs + 4096 + w * 1024);
    union { float4 v[4]; float f[16]; } Ee, Pp;
#pragma unroll
    for (int j = 0; j < 4; ++j) {
      Ee.v[j] = *(const float4*)(eprow + k0 + j * 4);
      Pp.v[j] = *(const float4*)(pprow + k0 + j * 4);
    }
    union { ushort8v v[2]; u16 s[16]; } R;
#pragma unroll
    for (int j = 0; j < 16; ++j) {
      float x = Ee.f[j] + Pp.f[j];
      float s = x * __builtin_amdgcn_rcpf(1.0f + __expf(-x));
      R.s[j] = f2bf(s);
    }
    *(ushort8v*)awp = R.v[0];
    *(ushort8v*)(awp + 8) = R.v[1];
    __syncthreads();

    short8 a[4], bb[4];
#pragma unroll
    for (int m = 0; m < 4; ++m)
      a[m] = *(const short8*)&As[(wr * 64 + m * 16 + lr) * 40 + lk * 8];
#pragma unroll
    for (int n = 0; n < 4; ++n)
      bb[n] = *(const short8*)&Bs[(wc * 64 + n * 16 + lr) * 32 + lk * 8];
#pragma unroll
    for (int m = 0; m < 4; ++m)
#pragma unroll
      for (int n = 0; n < 4; ++n)
        acc[m][n] = __builtin_amdgcn_mfma_f32_16x16x32_bf16(a[m], bb[n], acc[m][n], 0, 0, 0);
    __syncthreads();
  }

  const size_t mbase = (size_t)mb * 128;
#pragma unroll
  for (int m = 0; m < 4; ++m) {
    const size_t row = mbase + wr * 64 + m * 16 + lk * 4;
#pragma unroll
    for (int n = 0; n < 4; ++n) {
      const int col = n0 + wc * 64 + n * 16 + lr;
#pragma unroll
      for (int i = 0; i < 4; ++i)
        out[(row + i) * V_ + col] = acc[m][n][i];
    }
  }
}

extern "C" void kernel_launch(void* const* d_in, const int* in_sizes, int n_in,
                              void* d_out, int out_size, void* d_ws, size_t ws_size,
                              hipStream_t stream) {
  const float* enc = (const float*)d_in[0];   // [8,256,512]
  const float* pred = (const float*)d_in[1];  // [8,64,512]
  const float* We = (const float*)d_in[2];    // [640,512]
  const float* Wp = (const float*)d_in[3];    // [640,512]
  const float* Wo = (const float*)d_in[4];    // [1024,640]
  float* out = (float*)d_out;                 // [8,256,64,1024]

  char* ws = (char*)d_ws;
  u16* enc_bf = (u16*)ws;                     // 2,097,152 B
  u16* pred_bf = (u16*)(ws + 2097152);        //   524,288 B
  u16* We_bf = (u16*)(ws + 2621440);          //   655,360 B
  u16* Wp_bf = (u16*)(ws + 3276800);          //   655,360 B
  u16* Wo_bf = (u16*)(ws + 3932160);          // 1,310,720 B -> ends 5,242,880
  float* ep = (float*)(ws + 5242880);         // 5,242,880 B  [2048][640]
  float* pp = (float*)(ws + 10485760);        // 1,310,720 B  [512][640] -> ends 11,796,480
  u16* A_bf = (u16*)(ws + 12582912);          // 167,772,160 B [131072][640] -> ends 180,355,072

  cast_k<<<1024, 256, 0, stream>>>((const float4*)enc, (ushort4*)enc_bf, 262144);
  cast_k<<<256, 256, 0, stream>>>((const float4*)pred, (ushort4*)pred_bf, 65536);
  cast_k<<<320, 256, 0, stream>>>((const float4*)We, (ushort4*)We_bf, 81920);
  cast_k<<<320, 256, 0, stream>>>((const float4*)Wp, (ushort4*)Wp_bf, 81920);
  cast_k<<<640, 256, 0, stream>>>((const float4*)Wo, (ushort4*)Wo_bf, 163840);

  proj_k<<<dim3(16, 5), 256, 0, stream>>>(enc_bf, We_bf, ep);  // [2048][640]
  proj_k<<<dim3(4, 5), 256, 0, stream>>>(pred_bf, Wp_bf, pp);  // [512][640]

  if (ws_size >= 180355072ull) {
    silu_k<<<2048, 256, 0, stream>>>(ep, pp, A_bf, 10485760);
    gemm_k<<<8192, 256, 0, stream>>>(A_bf, Wo_bf, out);
  } else {
    joint_k<<<8192, 256, 0, stream>>>(ep, pp, Wo_bf, out);
  }
}

// Round 3
// 399.334 us; speedup vs baseline: 1.1199x; 1.1190x over previous
//
#include <hip/hip_runtime.h>

typedef unsigned short u16;
typedef __attribute__((ext_vector_type(8))) short short8;
typedef __attribute__((ext_vector_type(8))) unsigned short ushort8v;
typedef __attribute__((ext_vector_type(4))) float f32x4;

#define B_ 8
#define T_ 256
#define U_ 64
#define E_ 512
#define J_ 640
#define V_ 1024

__device__ __forceinline__ u16 f2bf(float f) {
  unsigned int u = __float_as_uint(f);
  u += 0x7fffu + ((u >> 16) & 1u);   // round-to-nearest-even
  return (u16)(u >> 16);
}

__device__ __forceinline__ void gload16(const void* g, void* l) {
  __builtin_amdgcn_global_load_lds((const __attribute__((address_space(1))) void*)g,
                                   (__attribute__((address_space(3))) void*)l,
                                   16, 0, 0);
}

// ---------------- cast fp32 -> bf16 ----------------
__global__ __launch_bounds__(256) void cast_k(const float4* __restrict__ src,
                                              ushort4* __restrict__ dst, int n4) {
  int i = blockIdx.x * 256 + threadIdx.x;
  int st = gridDim.x * 256;
  for (; i < n4; i += st) {
    float4 v = src[i];
    ushort4 o;
    o.x = f2bf(v.x); o.y = f2bf(v.y); o.z = f2bf(v.z); o.w = f2bf(v.w);
    dst[i] = o;
  }
}

// ---------------- projection GEMM (small, latency-tolerant) ----------------
__global__ __launch_bounds__(256) void proj_k(const u16* __restrict__ X,
                                              const u16* __restrict__ W,
                                              float* __restrict__ C) {
  __shared__ __align__(16) u16 As[128 * 32];
  __shared__ __align__(16) u16 Bs[128 * 32];
  const int tid = threadIdx.x;
  const int w = tid >> 6, lane = tid & 63;
  const int wr = w >> 1, wc = w & 1;
  const int m0 = blockIdx.x * 128, n0 = blockIdx.y * 128;
  const int lr = lane & 15, lk = lane >> 4;
  const int r4 = tid >> 2, kq = tid & 3;

  f32x4 acc[4][4] = {};

  for (int ks = 0; ks < E_ / 32; ++ks) {
    const int k0 = ks * 32;
    gload16(X + (size_t)(m0 + r4) * E_ + k0 + kq * 8, (char*)As + w * 1024);
    gload16(X + (size_t)(m0 + 64 + r4) * E_ + k0 + kq * 8, (char*)As + 4096 + w * 1024);
    gload16(W + (size_t)(n0 + r4) * E_ + k0 + kq * 8, (char*)Bs + w * 1024);
    gload16(W + (size_t)(n0 + 64 + r4) * E_ + k0 + kq * 8, (char*)Bs + 4096 + w * 1024);
    __syncthreads();
    short8 a[4], bb[4];
#pragma unroll
    for (int m = 0; m < 4; ++m)
      a[m] = *(const short8*)&As[(wr * 64 + m * 16 + lr) * 32 + lk * 8];
#pragma unroll
    for (int n = 0; n < 4; ++n)
      bb[n] = *(const short8*)&Bs[(wc * 64 + n * 16 + lr) * 32 + lk * 8];
#pragma unroll
    for (int m = 0; m < 4; ++m)
#pragma unroll
      for (int n = 0; n < 4; ++n)
        acc[m][n] = __builtin_amdgcn_mfma_f32_16x16x32_bf16(a[m], bb[n], acc[m][n], 0, 0, 0);
    __syncthreads();
  }

#pragma unroll
  for (int m = 0; m < 4; ++m) {
    const int row = m0 + wr * 64 + m * 16 + lk * 4;
#pragma unroll
    for (int n = 0; n < 4; ++n) {
      const int col = n0 + wc * 64 + n * 16 + lr;
#pragma unroll
      for (int i = 0; i < 4; ++i)
        C[(size_t)(row + i) * J_ + col] = acc[m][n][i];
    }
  }
}

// ---------------- A materializer: A[m][k] = bf16(silu(ep + pp)) ----------------
__global__ __launch_bounds__(256) void silu_k(const float* __restrict__ ep,
                                              const float* __restrict__ pp,
                                              u16* __restrict__ A, int nUnits) {
  int i = blockIdx.x * 256 + threadIdx.x;
  const int st = gridDim.x * 256;
  for (; i < nUnits; i += st) {
    const int m = i / 80;
    const int k0 = (i - m * 80) * 8;
    const int b = m >> 14;
    const int t = (m >> 6) & 255;
    const int uu = m & 63;
    const float* e = ep + (size_t)(b * T_ + t) * J_ + k0;
    const float* p = pp + (size_t)(b * U_ + uu) * J_ + k0;
    union { float4 v[2]; float f[8]; } Ee, Pp;
    Ee.v[0] = *(const float4*)e;      Ee.v[1] = *(const float4*)(e + 4);
    Pp.v[0] = *(const float4*)p;      Pp.v[1] = *(const float4*)(p + 4);
    union { ushort8v v; u16 s[8]; } R;
#pragma unroll
    for (int j = 0; j < 8; ++j) {
      float x = Ee.f[j] + Pp.f[j];
      float s = x * __builtin_amdgcn_rcpf(1.0f + __expf(-x));
      R.s[j] = f2bf(s);
    }
    *(ushort8v*)(A + (size_t)m * J_ + k0) = R.v;
  }
}

// ---------------- main GEMM: 256x256 tile, BK=32, 8 waves, 3-buffer counted-vmcnt pipeline --
// out[M=131072][1024] = A[M][640] @ Wo[1024][640]^T
#define NT 20   // 640/32 K-tiles
__global__ __launch_bounds__(512, 2) void gemm256_k(const u16* __restrict__ A,
                                                    const u16* __restrict__ Bw,
                                                    float* __restrict__ out) {
  // 3 buffers x (A-tile 16KB + B-tile 16KB) = 96 KiB
  __shared__ __align__(16) u16 As[3 * 8192];
  __shared__ __align__(16) u16 Bs[3 * 8192];
  const int tid = threadIdx.x;
  const int w = tid >> 6, lane = tid & 63;
  const int wr = w >> 2, wc = w & 3;            // 2M x 4N waves
  const int lr = lane & 15, lk = lane >> 4;

  // XCD-bijective swizzle: nwg=2048 = 8 XCDs x 256-chunk
  const int bid = blockIdx.x;
  const int wid = (bid & 7) * 256 + (bid >> 3);
  const int mb = wid >> 2, nb = wid & 3;        // nb inner: 4 N-blocks share A-panel in-XCD
  const size_t m0 = (size_t)mb * 256;
  const int n0 = nb * 256;

  // staging addressing: per pass, wave w covers rows w*16+(lane>>2), cols (lane&3)*8
  const int rr = lane >> 2;
  const int c8 = (lane & 3) * 8;
  const u16* aS = A + (m0 + w * 16 + rr) * J_ + c8;
  const u16* bS = Bw + (size_t)(n0 + w * 16 + rr) * J_ + c8;

  f32x4 acc[8][4] = {};

#define STAGE(tt, bb)                                                         \
  do {                                                                        \
    const int k0_ = (tt) * 32;                                                \
    char* ad_ = (char*)As + (bb) * 16384 + w * 1024;                          \
    char* bd_ = (char*)Bs + (bb) * 16384 + w * 1024;                          \
    gload16(aS + k0_, ad_);                                                   \
    gload16(aS + 128 * J_ + k0_, ad_ + 8192);                                 \
    gload16(bS + k0_, bd_);                                                   \
    gload16(bS + 128 * J_ + k0_, bd_ + 8192);                                 \
  } while (0)

  STAGE(0, 0);
  STAGE(1, 1);

  int cur = 0;
  for (int t = 0; t < NT; ++t) {
    if (t + 2 < NT) {
      const int nxt = cur + 2 >= 3 ? cur - 1 : cur + 2;   // (t+2)%3
      STAGE(t + 2, nxt);
    }
    // counted vmcnt: keep stages t+1,t+2 in flight across the barrier
    if (t < NT - 2)      asm volatile("s_waitcnt vmcnt(8)" ::: "memory");
    else if (t == NT - 2) asm volatile("s_waitcnt vmcnt(4)" ::: "memory");
    else                  asm volatile("s_waitcnt vmcnt(0)" ::: "memory");
    __builtin_amdgcn_s_barrier();
    __builtin_amdgcn_sched_barrier(0);

    const u16* Ab = As + cur * 8192;
    const u16* Bb = Bs + cur * 8192;
    short8 a[8], b[4];
#pragma unroll
    for (int m = 0; m < 8; ++m)
      a[m] = *(const short8*)&Ab[(wr * 128 + m * 16 + lr) * 32 + lk * 8];
#pragma unroll
    for (int n = 0; n < 4; ++n)
      b[n] = *(const short8*)&Bb[(wc * 64 + n * 16 + lr) * 32 + lk * 8];

    __builtin_amdgcn_s_setprio(1);
#pragma unroll
    for (int m = 0; m < 8; ++m)
#pragma unroll
      for (int n = 0; n < 4; ++n)
        acc[m][n] = __builtin_amdgcn_mfma_f32_16x16x32_bf16(a[m], b[n], acc[m][n], 0, 0, 0);
    __builtin_amdgcn_s_setprio(0);

    __builtin_amdgcn_sched_barrier(0);
    __builtin_amdgcn_s_barrier();   // all waves done reading buf[cur] -> next iter may overwrite
    cur = cur == 2 ? 0 : cur + 1;
  }
#undef STAGE

#pragma unroll
  for (int m = 0; m < 8; ++m) {
    const size_t row = m0 + wr * 128 + m * 16 + lk * 4;
#pragma unroll
    for (int n = 0; n < 4; ++n) {
      const int col = n0 + wc * 64 + n * 16 + lr;
#pragma unroll
      for (int i = 0; i < 4; ++i)
        out[(row + i) * V_ + col] = acc[m][n][i];
    }
  }
}

// ---------------- fallback fused kernel (round-1) if ws too small ----------------
__global__ __launch_bounds__(256) void joint_k(const float* __restrict__ ep,
                                               const float* __restrict__ pp,
                                               const u16* __restrict__ Wo,
                                               float* __restrict__ out) {
  __shared__ __align__(16) u16 As[128 * 40];
  __shared__ __align__(16) u16 Bs[128 * 32];
  const int tid = threadIdx.x;
  const int w = tid >> 6, lane = tid & 63;
  const int wr = w >> 1, wc = w & 1;
  const int bid = blockIdx.x;
  const int nb = bid & 7;
  const int mb = bid >> 3;
  const int b = mb >> 7;
  const int t0 = (mb & 127) * 2;
  const int n0 = nb * 128;
  const int lr = lane & 15, lk = lane >> 4;
  const int r = tid >> 1, h = tid & 1;
  const float* eprow = ep + (size_t)((b * T_ + t0 + (r >> 6)) * J_ + h * 16);
  const float* pprow = pp + (size_t)((b * U_ + (r & 63)) * J_ + h * 16);
  u16* awp = &As[r * 40 + h * 16];
  const int r4 = tid >> 2, kq = tid & 3;

  f32x4 acc[4][4] = {};

  for (int ks = 0; ks < J_ / 32; ++ks) {
    const int k0 = ks * 32;
    gload16(Wo + (size_t)(n0 + r4) * J_ + k0 + kq * 8, (char*)Bs + w * 1024);
    gload16(Wo + (size_t)(n0 + 64 + r4) * J_ + k0 + kq * 8, (char*)Bs + 4096 + w * 1024);
    union { float4 v[4]; float f[16]; } Ee, Pp;
#pragma unroll
    for (int j = 0; j < 4; ++j) {
      Ee.v[j] = *(const float4*)(eprow + k0 + j * 4);
      Pp.v[j] = *(const float4*)(pprow + k0 + j * 4);
    }
    union { ushort8v v[2]; u16 s[16]; } R;
#pragma unroll
    for (int j = 0; j < 16; ++j) {
      float x = Ee.f[j] + Pp.f[j];
      float s = x * __builtin_amdgcn_rcpf(1.0f + __expf(-x));
      R.s[j] = f2bf(s);
    }
    *(ushort8v*)awp = R.v[0];
    *(ushort8v*)(awp + 8) = R.v[1];
    __syncthreads();

    short8 a[4], bb[4];
#pragma unroll
    for (int m = 0; m < 4; ++m)
      a[m] = *(const short8*)&As[(wr * 64 + m * 16 + lr) * 40 + lk * 8];
#pragma unroll
    for (int n = 0; n < 4; ++n)
      bb[n] = *(const short8*)&Bs[(wc * 64 + n * 16 + lr) * 32 + lk * 8];
#pragma unroll
    for (int m = 0; m < 4; ++m)
#pragma unroll
      for (int n = 0; n < 4; ++n)
        acc[m][n] = __builtin_amdgcn_mfma_f32_16x16x32_bf16(a[m], bb[n], acc[m][n], 0, 0, 0);
    __syncthreads();
  }

  const size_t mbase = (size_t)mb * 128;
#pragma unroll
  for (int m = 0; m < 4; ++m) {
    const size_t row = mbase + wr * 64 + m * 16 + lk * 4;
#pragma unroll
    for (int n = 0; n < 4; ++n) {
      const int col = n0 + wc * 64 + n * 16 + lr;
#pragma unroll
      for (int i = 0; i < 4; ++i)
        out[(row + i) * V_ + col] = acc[m][n][i];
    }
  }
}

extern "C" void kernel_launch(void* const* d_in, const int* in_sizes, int n_in,
                              void* d_out, int out_size, void* d_ws, size_t ws_size,
                              hipStream_t stream) {
  const float* enc = (const float*)d_in[0];   // [8,256,512]
  const float* pred = (const float*)d_in[1];  // [8,64,512]
  const float* We = (const float*)d_in[2];    // [640,512]
  const float* Wp = (const float*)d_in[3];    // [640,512]
  const float* Wo = (const float*)d_in[4];    // [1024,640]
  float* out = (float*)d_out;                 // [8,256,64,1024]

  char* ws = (char*)d_ws;
  u16* enc_bf = (u16*)ws;                     // 2,097,152 B
  u16* pred_bf = (u16*)(ws + 2097152);        //   524,288 B
  u16* We_bf = (u16*)(ws + 2621440);          //   655,360 B
  u16* Wp_bf = (u16*)(ws + 3276800);          //   655,360 B
  u16* Wo_bf = (u16*)(ws + 3932160);          // 1,310,720 B -> ends 5,242,880
  float* ep = (float*)(ws + 5242880);         // 5,242,880 B  [2048][640]
  float* pp = (float*)(ws + 10485760);        // 1,310,720 B  [512][640] -> ends 11,796,480
  u16* A_bf = (u16*)(ws + 12582912);          // 167,772,160 B [131072][640] -> ends 180,355,072

  cast_k<<<1024, 256, 0, stream>>>((const float4*)enc, (ushort4*)enc_bf, 262144);
  cast_k<<<256, 256, 0, stream>>>((const float4*)pred, (ushort4*)pred_bf, 65536);
  cast_k<<<320, 256, 0, stream>>>((const float4*)We, (ushort4*)We_bf, 81920);
  cast_k<<<320, 256, 0, stream>>>((const float4*)Wp, (ushort4*)Wp_bf, 81920);
  cast_k<<<640, 256, 0, stream>>>((const float4*)Wo, (ushort4*)Wo_bf, 163840);

  proj_k<<<dim3(16, 5), 256, 0, stream>>>(enc_bf, We_bf, ep);  // [2048][640]
  proj_k<<<dim3(4, 5), 256, 0, stream>>>(pred_bf, Wp_bf, pp);  // [512][640]

  if (ws_size >= 180355072ull) {
    silu_k<<<2048, 256, 0, stream>>>(ep, pp, A_bf, 10485760);
    gemm256_k<<<2048, 512, 0, stream>>>(A_bf, Wo_bf, out);
  } else {
    joint_k<<<8192, 256, 0, stream>>>(ep, pp, Wo_bf, out);
  }
}

// Round 4
// 385.291 us; speedup vs baseline: 1.1608x; 1.0364x over previous
//
#include <hip/hip_runtime.h>

typedef unsigned short u16;
typedef __attribute__((ext_vector_type(8))) short short8;
typedef __attribute__((ext_vector_type(8))) unsigned short ushort8v;
typedef __attribute__((ext_vector_type(4))) float f32x4;

#define B_ 8
#define T_ 256
#define U_ 64
#define E_ 512
#define J_ 640
#define V_ 1024

__device__ __forceinline__ u16 f2bf(float f) {
  unsigned int u = __float_as_uint(f);
  u += 0x7fffu + ((u >> 16) & 1u);   // round-to-nearest-even
  return (u16)(u >> 16);
}

__device__ __forceinline__ void gload16(const void* g, void* l) {
  __builtin_amdgcn_global_load_lds((const __attribute__((address_space(1))) void*)g,
                                   (__attribute__((address_space(3))) void*)l,
                                   16, 0, 0);
}

// ---------------- fused cast fp32 -> bf16 for all 5 inputs (dsts contiguous in ws) --------
__global__ __launch_bounds__(256) void cast5_k(const float4* __restrict__ s0,
                                               const float4* __restrict__ s1,
                                               const float4* __restrict__ s2,
                                               const float4* __restrict__ s3,
                                               const float4* __restrict__ s4,
                                               ushort4* __restrict__ dst) {
  int i = blockIdx.x * 256 + threadIdx.x;
  const int st = gridDim.x * 256;
  for (; i < 655360; i += st) {
    const float4* s; int off;
    if (i < 262144)      { s = s0; off = 0; }
    else if (i < 327680) { s = s1; off = 262144; }
    else if (i < 409600) { s = s2; off = 327680; }
    else if (i < 491520) { s = s3; off = 409600; }
    else                 { s = s4; off = 491520; }
    float4 v = s[i - off];
    ushort4 o;
    o.x = f2bf(v.x); o.y = f2bf(v.y); o.z = f2bf(v.z); o.w = f2bf(v.w);
    dst[i] = o;
  }
}

// ---------------- projection GEMM (small, latency-tolerant) ----------------
__global__ __launch_bounds__(256) void proj_k(const u16* __restrict__ X,
                                              const u16* __restrict__ W,
                                              float* __restrict__ C) {
  __shared__ __align__(16) u16 As[128 * 32];
  __shared__ __align__(16) u16 Bs[128 * 32];
  const int tid = threadIdx.x;
  const int w = tid >> 6, lane = tid & 63;
  const int wr = w >> 1, wc = w & 1;
  const int m0 = blockIdx.x * 128, n0 = blockIdx.y * 128;
  const int lr = lane & 15, lk = lane >> 4;
  const int r4 = tid >> 2, kq = tid & 3;

  f32x4 acc[4][4] = {};

  for (int ks = 0; ks < E_ / 32; ++ks) {
    const int k0 = ks * 32;
    gload16(X + (size_t)(m0 + r4) * E_ + k0 + kq * 8, (char*)As + w * 1024);
    gload16(X + (size_t)(m0 + 64 + r4) * E_ + k0 + kq * 8, (char*)As + 4096 + w * 1024);
    gload16(W + (size_t)(n0 + r4) * E_ + k0 + kq * 8, (char*)Bs + w * 1024);
    gload16(W + (size_t)(n0 + 64 + r4) * E_ + k0 + kq * 8, (char*)Bs + 4096 + w * 1024);
    __syncthreads();
    short8 a[4], bb[4];
#pragma unroll
    for (int m = 0; m < 4; ++m)
      a[m] = *(const short8*)&As[(wr * 64 + m * 16 + lr) * 32 + lk * 8];
#pragma unroll
    for (int n = 0; n < 4; ++n)
      bb[n] = *(const short8*)&Bs[(wc * 64 + n * 16 + lr) * 32 + lk * 8];
#pragma unroll
    for (int m = 0; m < 4; ++m)
#pragma unroll
      for (int n = 0; n < 4; ++n)
        acc[m][n] = __builtin_amdgcn_mfma_f32_16x16x32_bf16(a[m], bb[n], acc[m][n], 0, 0, 0);
    __syncthreads();
  }

#pragma unroll
  for (int m = 0; m < 4; ++m) {
    const int row = m0 + wr * 64 + m * 16 + lk * 4;
#pragma unroll
    for (int n = 0; n < 4; ++n) {
      const int col = n0 + wc * 64 + n * 16 + lr;
#pragma unroll
      for (int i = 0; i < 4; ++i)
        C[(size_t)(row + i) * J_ + col] = acc[m][n][i];
    }
  }
}

// ---------------- A materializer: A[m][k] = bf16(silu(ep + pp)) ----------------
__global__ __launch_bounds__(256) void silu_k(const float* __restrict__ ep,
                                              const float* __restrict__ pp,
                                              u16* __restrict__ A, int nUnits) {
  int i = blockIdx.x * 256 + threadIdx.x;
  const int st = gridDim.x * 256;
  for (; i < nUnits; i += st) {
    const int m = i / 80;
    const int k0 = (i - m * 80) * 8;
    const int b = m >> 14;
    const int t = (m >> 6) & 255;
    const int uu = m & 63;
    const float* e = ep + (size_t)(b * T_ + t) * J_ + k0;
    const float* p = pp + (size_t)(b * U_ + uu) * J_ + k0;
    union { float4 v[2]; float f[8]; } Ee, Pp;
    Ee.v[0] = *(const float4*)e;      Ee.v[1] = *(const float4*)(e + 4);
    Pp.v[0] = *(const float4*)p;      Pp.v[1] = *(const float4*)(p + 4);
    union { ushort8v v; u16 s[8]; } R;
#pragma unroll
    for (int j = 0; j < 8; ++j) {
      float x = Ee.f[j] + Pp.f[j];
      float s = x * __builtin_amdgcn_rcpf(1.0f + __expf(-x));
      R.s[j] = f2bf(s);
    }
    *(ushort8v*)(A + (size_t)m * J_ + k0) = R.v;
  }
}

// ---------------- main GEMM: 256x256 tile, BK=32, 8 waves, 3-buffer counted-vmcnt pipeline --
// T2 XOR-swizzle: LDS tile [256 rows][4 chunks of 16B]; data chunk c stored at chunk' = c ^ ((row>>1)&3).
// Write side: global_load_lds dest linear; per-lane SOURCE chunk permuted (m173 pattern).
// Read side: chunk_read = lk ^ ((lr>>1)&3). 16 frag lanes -> all 8 bank-groups 2x = conflict-free.
#define NT 20   // 640/32 K-tiles
__global__ __launch_bounds__(512, 2) void gemm256_k(const u16* __restrict__ A,
                                                    const u16* __restrict__ Bw,
                                                    float* __restrict__ out) {
  __shared__ __align__(16) u16 As[3 * 8192];
  __shared__ __align__(16) u16 Bs[3 * 8192];
  const int tid = threadIdx.x;
  const int w = tid >> 6, lane = tid & 63;
  const int wr = w >> 2, wc = w & 3;            // 2M x 4N waves
  const int lr = lane & 15, lk = lane >> 4;
  const int sx = (lr >> 1) & 3;                 // read-side swizzle term

  // XCD-bijective swizzle: nwg=2048 = 8 XCDs x 256-chunk
  const int bid = blockIdx.x;
  const int wid = (bid & 7) * 256 + (bid >> 3);
  const int mb = wid >> 2, nb = wid & 3;
  const size_t m0 = (size_t)mb * 256;
  const int n0 = nb * 256;

  // staging: wave w covers rows w*16+(lane>>2); source chunk permuted for swizzle
  const int rr = lane >> 2;
  const int c8s = (((lane & 3) ^ ((lane >> 3) & 3))) * 8;   // swizzled source chunk (elems)
  const u16* aS = A + (m0 + w * 16 + rr) * J_ + c8s;
  const u16* bS = Bw + (size_t)(n0 + w * 16 + rr) * J_ + c8s;

  f32x4 acc[8][4] = {};

#define STAGE(tt, bb)                                                         \
  do {                                                                        \
    const int k0_ = (tt) * 32;                                                \
    char* ad_ = (char*)As + (bb) * 16384 + w * 1024;                          \
    char* bd_ = (char*)Bs + (bb) * 16384 + w * 1024;                          \
    gload16(aS + k0_, ad_);                                                   \
    gload16(aS + 128 * J_ + k0_, ad_ + 8192);                                 \
    gload16(bS + k0_, bd_);                                                   \
    gload16(bS + 128 * J_ + k0_, bd_ + 8192);                                 \
  } while (0)

  STAGE(0, 0);
  STAGE(1, 1);

  int cur = 0;
  for (int t = 0; t < NT; ++t) {
    if (t + 2 < NT) {
      const int nxt = cur + 2 >= 3 ? cur - 1 : cur + 2;   // (t+2)%3
      STAGE(t + 2, nxt);
    }
    // counted vmcnt: keep stages t+1,t+2 (8 loads) in flight across the barrier
    if (t < NT - 2)      asm volatile("s_waitcnt vmcnt(8)" ::: "memory");
    else if (t == NT - 2) asm volatile("s_waitcnt vmcnt(4)" ::: "memory");
    else                  asm volatile("s_waitcnt vmcnt(0)" ::: "memory");
    __builtin_amdgcn_s_barrier();
    __builtin_amdgcn_sched_barrier(0);

    const u16* Ab = As + cur * 8192;
    const u16* Bb = Bs + cur * 8192;
    short8 a[8], b[4];
#pragma unroll
    for (int m = 0; m < 8; ++m)
      a[m] = *(const short8*)&Ab[(wr * 128 + m * 16 + lr) * 32 + (lk ^ sx) * 8];
#pragma unroll
    for (int n = 0; n < 4; ++n)
      b[n] = *(const short8*)&Bb[(wc * 64 + n * 16 + lr) * 32 + (lk ^ sx) * 8];

    __builtin_amdgcn_s_setprio(1);
#pragma unroll
    for (int m = 0; m < 8; ++m)
#pragma unroll
      for (int n = 0; n < 4; ++n)
        acc[m][n] = __builtin_amdgcn_mfma_f32_16x16x32_bf16(a[m], b[n], acc[m][n], 0, 0, 0);
    __builtin_amdgcn_s_setprio(0);

    __builtin_amdgcn_sched_barrier(0);
    __builtin_amdgcn_s_barrier();   // all waves done reading buf[cur]
    cur = cur == 2 ? 0 : cur + 1;
  }
#undef STAGE

#pragma unroll
  for (int m = 0; m < 8; ++m) {
    const size_t row = m0 + wr * 128 + m * 16 + lk * 4;
#pragma unroll
    for (int n = 0; n < 4; ++n) {
      const int col = n0 + wc * 64 + n * 16 + lr;
#pragma unroll
      for (int i = 0; i < 4; ++i)
        out[(row + i) * V_ + col] = acc[m][n][i];
    }
  }
}

// ---------------- fallback fused kernel (round-1) if ws too small ----------------
__global__ __launch_bounds__(256) void joint_k(const float* __restrict__ ep,
                                               const float* __restrict__ pp,
                                               const u16* __restrict__ Wo,
                                               float* __restrict__ out) {
  __shared__ __align__(16) u16 As[128 * 40];
  __shared__ __align__(16) u16 Bs[128 * 32];
  const int tid = threadIdx.x;
  const int w = tid >> 6, lane = tid & 63;
  const int wr = w >> 1, wc = w & 1;
  const int bid = blockIdx.x;
  const int nb = bid & 7;
  const int mb = bid >> 3;
  const int b = mb >> 7;
  const int t0 = (mb & 127) * 2;
  const int n0 = nb * 128;
  const int lr = lane & 15, lk = lane >> 4;
  const int r = tid >> 1, h = tid & 1;
  const float* eprow = ep + (size_t)((b * T_ + t0 + (r >> 6)) * J_ + h * 16);
  const float* pprow = pp + (size_t)((b * U_ + (r & 63)) * J_ + h * 16);
  u16* awp = &As[r * 40 + h * 16];
  const int r4 = tid >> 2, kq = tid & 3;

  f32x4 acc[4][4] = {};

  for (int ks = 0; ks < J_ / 32; ++ks) {
    const int k0 = ks * 32;
    gload16(Wo + (size_t)(n0 + r4) * J_ + k0 + kq * 8, (char*)Bs + w * 1024);
    gload16(Wo + (size_t)(n0 + 64 + r4) * J_ + k0 + kq * 8, (char*)Bs + 4096 + w * 1024);
    union { float4 v[4]; float f[16]; } Ee, Pp;
#pragma unroll
    for (int j = 0; j < 4; ++j) {
      Ee.v[j] = *(const float4*)(eprow + k0 + j * 4);
      Pp.v[j] = *(const float4*)(pprow + k0 + j * 4);
    }
    union { ushort8v v[2]; u16 s[16]; } R;
#pragma unroll
    for (int j = 0; j < 16; ++j) {
      float x = Ee.f[j] + Pp.f[j];
      float s = x * __builtin_amdgcn_rcpf(1.0f + __expf(-x));
      R.s[j] = f2bf(s);
    }
    *(ushort8v*)awp = R.v[0];
    *(ushort8v*)(awp + 8) = R.v[1];
    __syncthreads();

    short8 a[4], bb[4];
#pragma unroll
    for (int m = 0; m < 4; ++m)
      a[m] = *(const short8*)&As[(wr * 64 + m * 16 + lr) * 40 + lk * 8];
#pragma unroll
    for (int n = 0; n < 4; ++n)
      bb[n] = *(const short8*)&Bs[(wc * 64 + n * 16 + lr) * 32 + lk * 8];
#pragma unroll
    for (int m = 0; m < 4; ++m)
#pragma unroll
      for (int n = 0; n < 4; ++n)
        acc[m][n] = __builtin_amdgcn_mfma_f32_16x16x32_bf16(a[m], bb[n], acc[m][n], 0, 0, 0);
    __syncthreads();
  }

  const size_t mbase = (size_t)mb * 128;
#pragma unroll
  for (int m = 0; m < 4; ++m) {
    const size_t row = mbase + wr * 64 + m * 16 + lk * 4;
#pragma unroll
    for (int n = 0; n < 4; ++n) {
      const int col = n0 + wc * 64 + n * 16 + lr;
#pragma unroll
      for (int i = 0; i < 4; ++i)
        out[(row + i) * V_ + col] = acc[m][n][i];
    }
  }
}

extern "C" void kernel_launch(void* const* d_in, const int* in_sizes, int n_in,
                              void* d_out, int out_size, void* d_ws, size_t ws_size,
                              hipStream_t stream) {
  const float* enc = (const float*)d_in[0];   // [8,256,512]
  const float* pred = (const float*)d_in[1];  // [8,64,512]
  const float* We = (const float*)d_in[2];    // [640,512]
  const float* Wp = (const float*)d_in[3];    // [640,512]
  const float* Wo = (const float*)d_in[4];    // [1024,640]
  float* out = (float*)d_out;                 // [8,256,64,1024]

  char* ws = (char*)d_ws;
  u16* enc_bf = (u16*)ws;                     // 2,097,152 B
  u16* pred_bf = (u16*)(ws + 2097152);        //   524,288 B
  u16* We_bf = (u16*)(ws + 2621440);          //   655,360 B
  u16* Wp_bf = (u16*)(ws + 3276800);          //   655,360 B
  u16* Wo_bf = (u16*)(ws + 3932160);          // 1,310,720 B -> ends 5,242,880
  float* ep = (float*)(ws + 5242880);         // 5,242,880 B  [2048][640]
  float* pp = (float*)(ws + 10485760);        // 1,310,720 B  [512][640] -> ends 11,796,480
  u16* A_bf = (u16*)(ws + 12582912);          // 167,772,160 B [131072][640] -> ends 180,355,072

  cast5_k<<<2048, 256, 0, stream>>>((const float4*)enc, (const float4*)pred,
                                    (const float4*)We, (const float4*)Wp,
                                    (const float4*)Wo, (ushort4*)ws);

  proj_k<<<dim3(16, 5), 256, 0, stream>>>(enc_bf, We_bf, ep);  // [2048][640]
  proj_k<<<dim3(4, 5), 256, 0, stream>>>(pred_bf, Wp_bf, pp);  // [512][640]

  if (ws_size >= 180355072ull) {
    silu_k<<<2048, 256, 0, stream>>>(ep, pp, A_bf, 10485760);
    gemm256_k<<<2048, 512, 0, stream>>>(A_bf, Wo_bf, out);
  } else {
    joint_k<<<8192, 256, 0, stream>>>(ep, pp, Wo_bf, out);
  }
}